// Round 1
// baseline (405.149 us; speedup 1.0000x reference)
//
#include <hip/hip_runtime.h>

typedef _Float16 half8 __attribute__((ext_vector_type(8)));
typedef _Float16 half2v __attribute__((ext_vector_type(2)));
typedef float float4v __attribute__((ext_vector_type(4)));

#define C_IN 64
#define C_OUT 128
#define H_IN 256
#define W_IN 256
#define H_OUT 254
#define W_OUT 254

// ---------------------------------------------------------------------------
// Pack conv_weight (OIHW fp32, [128][64][3][3]) into fp16 Bp[co][k] with
// k = (kh*3+kw)*64 + cin   (K reordered so one K-step of 64 = one (kh,kw) tap)
// ---------------------------------------------------------------------------
__global__ void pack_w_kernel(const float* __restrict__ w, _Float16* __restrict__ Bp) {
    int idx = blockIdx.x * 256 + threadIdx.x;          // 128*576 = 73728
    if (idx >= C_OUT * 576) return;
    int co  = idx / 576;
    int kp  = idx - co * 576;
    int s   = kp >> 6;          // tap index 0..8
    int cin = kp & 63;
    int kh  = s / 3, kw = s - kh * 3;
    Bp[idx] = (_Float16)w[(co * 64 + cin) * 9 + kh * 3 + kw];
}

// XOR-swizzled LDS byte offset for [row][64 fp16] tiles (rows = 128 B).
// G4/T2: spreads the per-row 16B chunks across 8 bank groups.
__device__ __forceinline__ int swz(int row, int kbyte) {
    return row * 128 + (kbyte ^ ((row & 7) << 4));
}

// ---------------------------------------------------------------------------
// Fused conv + bias + min_c + tanh(tanh(.))
// Block: 128 px (2 output rows x 64 cols) x 128 out-channels, BK=64, 9 K-steps.
// 4 waves, each 64px x 64ch = 4x4 fragments of 16x16, mfma_f32_16x16x32_f16.
// grid: (ow_tile=4, oh_tile=127, n=16)
// ---------------------------------------------------------------------------
__global__ __launch_bounds__(256, 2)
void conv_min_tanh_kernel(const float* __restrict__ x,
                          const _Float16* __restrict__ Bp,
                          const float* __restrict__ bias,
                          float* __restrict__ out) {
    __shared__ _Float16 Alds[128 * 64];   // [px][cin]  swizzled, 16 KB
    __shared__ _Float16 Blds[128 * 64];   // [co][cin]  swizzled, 16 KB
    __shared__ float minbuf[2][128];      // per-ch-half per-pixel min

    const int tid  = threadIdx.x;
    const int ow0  = blockIdx.x * 64;
    const int oh0  = blockIdx.y * 2;
    const int nb   = blockIdx.z;

    const int wave = tid >> 6;
    const int lane = tid & 63;
    const int wr   = wave >> 1;       // pixel half   (0/1 -> px 0..63 / 64..127)
    const int wc   = wave & 1;        // channel half (0/1 -> ch 0..63 / 64..127)
    const int q    = lane >> 4;       // quarter
    const int lr   = lane & 15;

    float4v acc[4][4];
#pragma unroll
    for (int m = 0; m < 4; ++m)
#pragma unroll
        for (int n = 0; n < 4; ++n)
#pragma unroll
            for (int i = 0; i < 4; ++i) acc[m][n][i] = 0.0f;

    // staging roles
    const int spx = tid & 127;        // pixel this thread stages for A
    const int sgh = tid >> 7;         // cin half (0/1)
    const int sr  = spx >> 6, sc = spx & 63;
    const int sco = tid >> 1;         // B: channel row
    const int spart = tid & 1;        // B: k half (32 fp16)

    const int arow0 = wr * 64 + lr;
    const int brow0 = wc * 64 + lr;

    for (int s = 0; s < 9; ++s) {
        const int kh = s / 3, kw = s - kh * 3;   // uniform per block

        __syncthreads();   // previous compute done before overwrite

        // ---- stage A: x[n][cin][oh0+r+kh][ow0+c+kw] -> Alds[px][cin] fp16
        {
            int ih = oh0 + sr + kh;
            int iw = ow0 + sc + kw;
            if (iw > W_IN - 1) iw = W_IN - 1;    // clamp (invalid px never stored)
            const float* xp = x + (size_t)nb * (C_IN * H_IN * W_IN)
                                + (size_t)(sgh * 32) * (H_IN * W_IN)
                                + ih * W_IN + iw;
#pragma unroll
            for (int j = 0; j < 4; ++j) {
                int cin0 = sgh * 32 + j * 8;
                float f[8];
#pragma unroll
                for (int u = 0; u < 8; ++u) f[u] = xp[(size_t)u * (H_IN * W_IN)];
                xp += (size_t)8 * (H_IN * W_IN);
                half8 hv;
#pragma unroll
                for (int u = 0; u < 8; ++u) hv[u] = (_Float16)f[u];
                *(half8*)((char*)Alds + swz(spx, cin0 * 2)) = hv;
            }
        }

        // ---- stage B: Bp[co][s*64 + kk] -> Blds[co][kk]
        {
            const half8* bp = (const half8*)(Bp + (size_t)sco * 576 + s * 64 + spart * 32);
#pragma unroll
            for (int j = 0; j < 4; ++j) {
                half8 bv = bp[j];
                *(half8*)((char*)Blds + swz(sco, spart * 64 + j * 16)) = bv;
            }
        }

        __syncthreads();

        // ---- compute: 2 k-chunks of 32, 4x4 fragments
#pragma unroll
        for (int h = 0; h < 2; ++h) {
            const int kb = h * 64 + q * 16;
            half8 a[4], b[4];
#pragma unroll
            for (int m = 0; m < 4; ++m)
                a[m] = *(const half8*)((const char*)Alds + swz(arow0 + m * 16, kb));
#pragma unroll
            for (int n = 0; n < 4; ++n)
                b[n] = *(const half8*)((const char*)Blds + swz(brow0 + n * 16, kb));
#pragma unroll
            for (int m = 0; m < 4; ++m)
#pragma unroll
                for (int n = 0; n < 4; ++n)
                    acc[m][n] = __builtin_amdgcn_mfma_f32_16x16x32_f16(a[m], b[n], acc[m][n], 0, 0, 0);
        }
    }

    // ---- epilogue: + bias, min over channels, double tanh
    // D frag: col(channel-in-frag) = lane&15, row(pixel-in-frag) = q*4 + i
#pragma unroll
    for (int m = 0; m < 4; ++m) {
        float4v v;
#pragma unroll
        for (int n = 0; n < 4; ++n) {
            float bv = bias[wc * 64 + n * 16 + lr];
#pragma unroll
            for (int i = 0; i < 4; ++i) {
                float t = acc[m][n][i] + bv;
                v[i] = (n == 0) ? t : fminf(v[i], t);
            }
        }
        // min across the 16 channel-lanes
#pragma unroll
        for (int off = 1; off < 16; off <<= 1)
#pragma unroll
            for (int i = 0; i < 4; ++i)
                v[i] = fminf(v[i], __shfl_xor(v[i], off, 64));
        if (lr == 0) {
#pragma unroll
            for (int i = 0; i < 4; ++i)
                minbuf[wc][wr * 64 + m * 16 + q * 4 + i] = v[i];
        }
    }
    __syncthreads();

    if (tid < 128) {
        int pr = tid >> 6, pc = tid & 63;
        int ow = ow0 + pc;
        if (ow < W_OUT) {
            float mv = fminf(minbuf[0][tid], minbuf[1][tid]);
            float r  = tanhf(tanhf(mv));
            out[((size_t)nb * H_OUT + (oh0 + pr)) * W_OUT + ow] = r;
        }
    }
}

extern "C" void kernel_launch(void* const* d_in, const int* in_sizes, int n_in,
                              void* d_out, int out_size, void* d_ws, size_t ws_size,
                              hipStream_t stream) {
    const float* x    = (const float*)d_in[0];
    const float* w    = (const float*)d_in[1];
    const float* bias = (const float*)d_in[2];
    float* out        = (float*)d_out;
    _Float16* Bp      = (_Float16*)d_ws;   // 128*576*2 = 147456 B scratch

    pack_w_kernel<<<dim3(288), dim3(256), 0, stream>>>(w, Bp);
    conv_min_tanh_kernel<<<dim3(4, 127, 16), dim3(256), 0, stream>>>(x, Bp, bias, out);
}

// Round 2
// 346.032 us; speedup vs baseline: 1.1708x; 1.1708x over previous
//
#include <hip/hip_runtime.h>
#include <stdint.h>

typedef _Float16 half8 __attribute__((ext_vector_type(8)));
typedef float float4v __attribute__((ext_vector_type(4)));

#define C_IN 64
#define C_OUT 128
#define H_IN 256
#define W_IN 256
#define H_OUT 254
#define W_OUT 254

// ---------------------------------------------------------------------------
// Pack conv_weight (OIHW fp32, [128][64][3][3]) into fp16 Bp[co][k] with
// k = (kh*3+kw)*64 + cin   (K reordered so one K-step of 64 = one (kh,kw) tap)
// ---------------------------------------------------------------------------
__global__ void pack_w_kernel(const float* __restrict__ w, _Float16* __restrict__ Bp) {
    int idx = blockIdx.x * 256 + threadIdx.x;          // 128*576 = 73728
    if (idx >= C_OUT * 576) return;
    int co  = idx / 576;
    int kp  = idx - co * 576;
    int s   = kp >> 6;          // tap index 0..8
    int cin = kp & 63;
    int kh  = s / 3, kw = s - kh * 3;
    Bp[idx] = (_Float16)w[(co * 64 + cin) * 9 + kh * 3 + kw];
}

// ---------------------------------------------------------------------------
// Transpose x: NCHW fp32 -> NHWC fp16  (x16[n][h][w][c], c innermost = 128 B)
// grid (4 wtiles, 256 h, 16 n), block 256. LDS 64x65 fp32 (+1 pad).
// ---------------------------------------------------------------------------
__global__ __launch_bounds__(256)
void nchw_to_nhwc_kernel(const float* __restrict__ x, _Float16* __restrict__ x16) {
    __shared__ float t[64][65];
    const int tid = threadIdx.x;
    const int w0 = blockIdx.x * 64;
    const int h  = blockIdx.y;
    const int n  = blockIdx.z;

    const int c  = tid >> 2;            // 0..63
    const int wq = (tid & 3) * 16;      // 0,16,32,48
    const float* src = x + (((size_t)(n * 64 + c) * H_IN + h) * W_IN + w0 + wq);
#pragma unroll
    for (int j = 0; j < 4; ++j) {
        float4v v = *(const float4v*)(src + j * 4);
#pragma unroll
        for (int u = 0; u < 4; ++u) t[c][wq + j * 4 + u] = v[u];
    }
    __syncthreads();

    _Float16* dst = x16 + ((size_t)(n * 256 + h) * 256 + w0) * 64;
#pragma unroll
    for (int k = 0; k < 2; ++k) {
        int v = tid + k * 256;
        int w = v >> 3, c0 = (v & 7) * 8;
        half8 hv;
#pragma unroll
        for (int u = 0; u < 8; ++u) hv[u] = (_Float16)t[c0 + u][w];
        *(half8*)(dst + (size_t)w * 64 + c0) = hv;
    }
}

// XOR-swizzled LDS byte offset for [row][64 fp16] tiles (rows = 128 B).
__device__ __forceinline__ int swz(int row, int kbyte) {
    return row * 128 + (kbyte ^ ((row & 7) << 4));
}

// ---------------------------------------------------------------------------
// v2 fused conv + bias + min_c + tanh(tanh(.))
// Stage input tile ONCE (4 rows x 66 cols x 64 cin fp16 = 33 KB) via
// global_load_lds w=16 with pre-swizzled source; 9 taps read shifted LDS rows.
// B read directly from L2-resident packed weights into fragments (no LDS).
// Block: 128 px (2 rows x 64 cols) x 128 co, 4 waves each 64px x 64ch.
// grid: (4, 127, 16)
// ---------------------------------------------------------------------------
#define A_ROWS 264   // 4 * 66

__global__ __launch_bounds__(256, 4)
void conv_v2_kernel(const _Float16* __restrict__ x16,
                    const _Float16* __restrict__ Bp,
                    const float* __restrict__ bias,
                    float* __restrict__ out) {
    __shared__ __align__(16) _Float16 Alds[A_ROWS * 64];   // 33792 B, swizzled
    __shared__ float minbuf[2][128];

    const int tid  = threadIdx.x;
    const int lane = tid & 63;
    const int wave = tid >> 6;
    const int ow0  = blockIdx.x * 64;
    const int oh0  = blockIdx.y * 2;
    const int nb   = blockIdx.z;

    // ---- stage A tile: rows oh0..oh0+3, cols ow0..ow0+65, 64 cin, fp16
    // LDS linear dest; source address pre-swizzled so reads use swz().
    {
        const char* xb = (const char*)(x16 + (size_t)nb * (256 * 256 * 64));
        for (int i = tid; i < 2112; i += 256) {            // 2112 x 16 B = 33792
            int row = i >> 3;
            int kb  = (i & 7) << 4;
            int r   = (unsigned)row / 66u;
            int c   = row - r * 66;
            int ih  = oh0 + r;
            int iw  = ow0 + c; if (iw > W_IN - 1) iw = W_IN - 1;
            const char* src = xb + (((size_t)ih * 256 + iw) << 7)
                                 + (kb ^ ((row & 7) << 4));
            char* ldst = (char*)Alds + ((size_t)(i & ~63) << 4);   // wave-uniform
            __builtin_amdgcn_global_load_lds(
                (const __attribute__((address_space(1))) uint32_t*)src,
                (__attribute__((address_space(3))) uint32_t*)ldst,
                16, 0, 0);
        }
    }
    __syncthreads();

    const int wr = wave >> 1;       // pixel half (row of output pair)
    const int wc = wave & 1;        // channel half
    const int q  = lane >> 4;
    const int lr = lane & 15;

    float4v acc[4][4];
#pragma unroll
    for (int m = 0; m < 4; ++m)
#pragma unroll
        for (int n = 0; n < 4; ++n)
#pragma unroll
            for (int i = 0; i < 4; ++i) acc[m][n][i] = 0.0f;

    const char* bpbase = (const char*)Bp + (size_t)(wc * 64 + lr) * 1152;

#pragma unroll
    for (int s = 0; s < 9; ++s) {
        const int kh = s / 3, kw = s - kh * 3;
        const int arowbase = (wr + kh) * 66 + kw;
#pragma unroll
        for (int h = 0; h < 2; ++h) {
            const int kb = h * 64 + q * 16;
            half8 a[4], b[4];
#pragma unroll
            for (int n = 0; n < 4; ++n)
                b[n] = *(const half8*)(bpbase + (size_t)n * 16 * 1152 + s * 128 + kb);
#pragma unroll
            for (int m = 0; m < 4; ++m) {
                int row = arowbase + m * 16 + lr;
                a[m] = *(const half8*)((const char*)Alds + swz(row, kb));
            }
#pragma unroll
            for (int m = 0; m < 4; ++m)
#pragma unroll
                for (int n = 0; n < 4; ++n)
                    acc[m][n] = __builtin_amdgcn_mfma_f32_16x16x32_f16(a[m], b[n], acc[m][n], 0, 0, 0);
        }
    }

    // ---- epilogue: + bias, min over channels, double tanh
#pragma unroll
    for (int m = 0; m < 4; ++m) {
        float4v v;
#pragma unroll
        for (int n = 0; n < 4; ++n) {
            float bv = bias[wc * 64 + n * 16 + lr];
#pragma unroll
            for (int i = 0; i < 4; ++i) {
                float t = acc[m][n][i] + bv;
                v[i] = (n == 0) ? t : fminf(v[i], t);
            }
        }
#pragma unroll
        for (int off = 1; off < 16; off <<= 1)
#pragma unroll
            for (int i = 0; i < 4; ++i)
                v[i] = fminf(v[i], __shfl_xor(v[i], off, 64));
        if (lr == 0) {
#pragma unroll
            for (int i = 0; i < 4; ++i)
                minbuf[wc][wr * 64 + m * 16 + q * 4 + i] = v[i];
        }
    }
    __syncthreads();

    if (tid < 128) {
        int pr = tid >> 6, pc = tid & 63;
        int ow = ow0 + pc;
        if (ow < W_OUT) {
            float mv = fminf(minbuf[0][tid], minbuf[1][tid]);
            float r  = tanhf(tanhf(mv));
            out[((size_t)nb * H_OUT + (oh0 + pr)) * W_OUT + ow] = r;
        }
    }
}

// ---------------------------------------------------------------------------
// Round-1 fallback kernel (used only if ws_size can't hold x16)
// ---------------------------------------------------------------------------
__global__ __launch_bounds__(256, 2)
void conv_min_tanh_kernel(const float* __restrict__ x,
                          const _Float16* __restrict__ Bp,
                          const float* __restrict__ bias,
                          float* __restrict__ out) {
    __shared__ _Float16 Alds[128 * 64];
    __shared__ _Float16 Blds[128 * 64];
    __shared__ float minbuf[2][128];

    const int tid  = threadIdx.x;
    const int ow0  = blockIdx.x * 64;
    const int oh0  = blockIdx.y * 2;
    const int nb   = blockIdx.z;

    const int wave = tid >> 6;
    const int lane = tid & 63;
    const int wr   = wave >> 1;
    const int wc   = wave & 1;
    const int q    = lane >> 4;
    const int lr   = lane & 15;

    float4v acc[4][4];
#pragma unroll
    for (int m = 0; m < 4; ++m)
#pragma unroll
        for (int n = 0; n < 4; ++n)
#pragma unroll
            for (int i = 0; i < 4; ++i) acc[m][n][i] = 0.0f;

    const int spx = tid & 127;
    const int sgh = tid >> 7;
    const int sr  = spx >> 6, sc = spx & 63;
    const int sco = tid >> 1;
    const int spart = tid & 1;

    const int arow0 = wr * 64 + lr;
    const int brow0 = wc * 64 + lr;

    for (int s = 0; s < 9; ++s) {
        const int kh = s / 3, kw = s - kh * 3;
        __syncthreads();
        {
            int ih = oh0 + sr + kh;
            int iw = ow0 + sc + kw;
            if (iw > W_IN - 1) iw = W_IN - 1;
            const float* xp = x + (size_t)nb * (C_IN * H_IN * W_IN)
                                + (size_t)(sgh * 32) * (H_IN * W_IN)
                                + ih * W_IN + iw;
#pragma unroll
            for (int j = 0; j < 4; ++j) {
                int cin0 = sgh * 32 + j * 8;
                float f[8];
#pragma unroll
                for (int u = 0; u < 8; ++u) f[u] = xp[(size_t)u * (H_IN * W_IN)];
                xp += (size_t)8 * (H_IN * W_IN);
                half8 hv;
#pragma unroll
                for (int u = 0; u < 8; ++u) hv[u] = (_Float16)f[u];
                *(half8*)((char*)Alds + swz(spx, cin0 * 2)) = hv;
            }
        }
        {
            const half8* bp = (const half8*)(Bp + (size_t)sco * 576 + s * 64 + spart * 32);
#pragma unroll
            for (int j = 0; j < 4; ++j) {
                half8 bv = bp[j];
                *(half8*)((char*)Blds + swz(sco, spart * 64 + j * 16)) = bv;
            }
        }
        __syncthreads();
#pragma unroll
        for (int h = 0; h < 2; ++h) {
            const int kb = h * 64 + q * 16;
            half8 a[4], b[4];
#pragma unroll
            for (int m = 0; m < 4; ++m)
                a[m] = *(const half8*)((const char*)Alds + swz(arow0 + m * 16, kb));
#pragma unroll
            for (int n = 0; n < 4; ++n)
                b[n] = *(const half8*)((const char*)Blds + swz(brow0 + n * 16, kb));
#pragma unroll
            for (int m = 0; m < 4; ++m)
#pragma unroll
                for (int n = 0; n < 4; ++n)
                    acc[m][n] = __builtin_amdgcn_mfma_f32_16x16x32_f16(a[m], b[n], acc[m][n], 0, 0, 0);
        }
    }

#pragma unroll
    for (int m = 0; m < 4; ++m) {
        float4v v;
#pragma unroll
        for (int n = 0; n < 4; ++n) {
            float bv = bias[wc * 64 + n * 16 + lr];
#pragma unroll
            for (int i = 0; i < 4; ++i) {
                float t = acc[m][n][i] + bv;
                v[i] = (n == 0) ? t : fminf(v[i], t);
            }
        }
#pragma unroll
        for (int off = 1; off < 16; off <<= 1)
#pragma unroll
            for (int i = 0; i < 4; ++i)
                v[i] = fminf(v[i], __shfl_xor(v[i], off, 64));
        if (lr == 0) {
#pragma unroll
            for (int i = 0; i < 4; ++i)
                minbuf[wc][wr * 64 + m * 16 + q * 4 + i] = v[i];
        }
    }
    __syncthreads();

    if (tid < 128) {
        int pr = tid >> 6, pc = tid & 63;
        int ow = ow0 + pc;
        if (ow < W_OUT) {
            float mv = fminf(minbuf[0][tid], minbuf[1][tid]);
            float r  = tanhf(tanhf(mv));
            out[((size_t)nb * H_OUT + (oh0 + pr)) * W_OUT + ow] = r;
        }
    }
}

extern "C" void kernel_launch(void* const* d_in, const int* in_sizes, int n_in,
                              void* d_out, int out_size, void* d_ws, size_t ws_size,
                              hipStream_t stream) {
    const float* x    = (const float*)d_in[0];
    const float* w    = (const float*)d_in[1];
    const float* bias = (const float*)d_in[2];
    float* out        = (float*)d_out;

    const size_t x16_bytes = (size_t)16 * 256 * 256 * 64 * 2;   // 134 MB
    const size_t bp_bytes  = (size_t)128 * 576 * 2;             // 147 KB

    if (ws_size >= x16_bytes + bp_bytes) {
        _Float16* x16 = (_Float16*)d_ws;
        _Float16* Bp  = (_Float16*)((char*)d_ws + x16_bytes);
        pack_w_kernel<<<dim3(288), dim3(256), 0, stream>>>(w, Bp);
        nchw_to_nhwc_kernel<<<dim3(4, 256, 16), dim3(256), 0, stream>>>(x, x16);
        conv_v2_kernel<<<dim3(4, 127, 16), dim3(256), 0, stream>>>(x16, Bp, bias, out);
    } else {
        _Float16* Bp = (_Float16*)d_ws;
        pack_w_kernel<<<dim3(288), dim3(256), 0, stream>>>(w, Bp);
        conv_min_tanh_kernel<<<dim3(4, 127, 16), dim3(256), 0, stream>>>(x, Bp, bias, out);
    }
}